// Round 5
// baseline (286.254 us; speedup 1.0000x reference)
//
#include <hip/hip_runtime.h>

#define N_NODES 50000
#define N_EDGES 800000
#define NE4 (N_EDGES / 4)
#define NMASKW 1568          // ceil(50000/32)=1563, padded
#define MAXN1 192            // f1 slots (LDS acc rows); deg(node1)~16
#define S2MAX 1024           // f2 slot cap (actual ~254)
#define DMAX  4096           // eD cap (actual ~256)
#define CMAX  16384          // eC cap (actual ~4096)
#define E1MAX 1024           // e1src cap (actual ~16)
#define GRID 64              // few blocks -> cheap barrier arrivals; 1 block/CU co-resident
#define TPB 1024             // 16 waves/block; 65536 threads total for scans
#define NW (TPB / 64)
#define TOTW (GRID * NW)     // 1024 waves
#define EDCHUNK 512

// Cross-phase non-atomic WRITES: write-through to coherence point. Cross-phase
// READS are plain cached (safe: every buffer is write-phase -> barrier -> read-
// phase, never read before its write phase, so no XCD holds a stale copy).
#define AS(p, v) __hip_atomic_store((p), (v), __ATOMIC_RELAXED, __HIP_MEMORY_SCOPE_AGENT)
#define ALD(p)   __hip_atomic_load((p), __ATOMIC_RELAXED, __HIP_MEMORY_SCOPE_AGENT)

__device__ __forceinline__ float lrelu(float v) { return v >= 0.f ? v : 0.01f * v; }
__device__ __forceinline__ bool mtest(const unsigned int* m, int i) {
    return (m[i >> 5] >> (i & 31)) & 1u;
}

struct Params {
    const float* x; const int* src; const int* dst;
    const float* W0; const float* b0; const float* W1; const float* b1;
    const float* W2; const float* b2; const float* W3; const float* b3;
    float* out;
    unsigned int* f1m; unsigned int* f2m; unsigned int* f3m;
    int* cntE1; int* cntD; int* cntC; int* cnt1; int* cnt2;
    int* bar; int* rel;      // separate 256B lines: arrivals vs release spin
    float* agg0; float* agg1c; float* t2c;
    int* e1src; int2* eD; int2* eC; int* pos1; int* pos2;
};

// Last-arriver-release barrier: arrivals RMW 'bar' (64 adds, no readers on that
// line); last arriver (detected from fetch_add return) stores 'rel'; others
// spin-READ 'rel' with backoff. No RMW/read contention, no cache maintenance.
__device__ __forceinline__ void gsync(int* bar, int* rel, int ph) {
    __syncthreads();
    if (threadIdx.x == 0) {
        int old = __hip_atomic_fetch_add(bar, 1, __ATOMIC_RELAXED, __HIP_MEMORY_SCOPE_AGENT);
        if (old == ph * GRID - 1) {
            AS(rel, ph);
        } else {
            while (ALD(rel) < ph) __builtin_amdgcn_s_sleep(8);
        }
    }
    __syncthreads();
}

// P1 dst==1 -> f1/pos1/e1src          P2 f1[dst] -> eD,f2/pos2(+agg1c row zero)
// P3 f2[dst] -> eC,f3(+agg0 zero)     P4 f3[dst] -> agg0 += x[src]
// P5 eC wave/edge -> agg1c atomics    P6 layer12 -> t2c    P7 tail (block 0)
__global__ __launch_bounds__(TPB, 1) void gcn_k(Params p) {
    __shared__ __align__(16) float smem[MAXN1 * 64 + MAXN1];   // 49,920 B
    __shared__ int2 eDs[EDCHUNK];                              // 4 KB (P7 staging)
    const int tid = threadIdx.x;
    const int gid = blockIdx.x * TPB + tid;
    const int T = GRID * TPB;
    unsigned int* msk = (unsigned int*)smem;
    const int4* dst4 = (const int4*)p.dst;

    // ---- P1: dst==1 -> e1src, f1 bit, pos1 slot ----
    for (int t = gid; t < NE4; t += T) {
        int4 d4 = dst4[t];
        int dv[4] = { d4.x, d4.y, d4.z, d4.w };
#pragma unroll
        for (int k = 0; k < 4; ++k) {
            if (dv[k] == 1) {
                int ss = p.src[t * 4 + k];
                int q = atomicAdd(p.cntE1, 1);
                if (q < E1MAX) AS(&p.e1src[q], ss);
                unsigned int bit = 1u << (ss & 31);
                unsigned int old = atomicOr(&p.f1m[ss >> 5], bit);
                if (!(old & bit)) {
                    int q1 = atomicAdd(p.cnt1, 1);
                    AS(&p.pos1[ss], q1);
                }
            }
        }
    }
    gsync(p.bar, p.rel, 1);

    // ---- P2: f1[dst] -> eD=(src, pos1[dst]); f2 first-setter: pos2 + zero agg1c row ----
    for (int k = tid; k < NMASKW; k += TPB) msk[k] = p.f1m[k];
    __syncthreads();
    for (int t = gid; t < NE4; t += T) {
        int4 d4 = dst4[t];
        int dv[4] = { d4.x, d4.y, d4.z, d4.w };
#pragma unroll
        for (int k = 0; k < 4; ++k) {
            if (mtest(msk, dv[k])) {
                int ss = p.src[t * 4 + k];
                unsigned int bit = 1u << (ss & 31);
                unsigned int old = atomicOr(&p.f2m[ss >> 5], bit);
                if (!(old & bit)) {
                    int q2 = atomicAdd(p.cnt2, 1);
                    if (q2 < S2MAX) {
                        AS(&p.pos2[ss], q2);
                        float* z = p.agg1c + (size_t)q2 * 64;
#pragma unroll
                        for (int r = 0; r < 64; ++r) AS(&z[r], 0.f);
                    }
                }
                int q = atomicAdd(p.cntD, 1);
                if (q < DMAX) {
                    unsigned long long ev = (unsigned long long)(unsigned int)ss |
                        ((unsigned long long)(unsigned int)p.pos1[dv[k]] << 32);
                    AS((unsigned long long*)&p.eD[q], ev);
                }
            }
        }
    }
    gsync(p.bar, p.rel, 2);

    // ---- P3: f2[dst] -> eC=(src, pos2[dst]); f3 first-setter: zero agg0[src] ----
    for (int k = tid; k < NMASKW; k += TPB) msk[k] = p.f2m[k];
    __syncthreads();
    for (int t = gid; t < NE4; t += T) {
        int4 d4 = dst4[t];
        int dv[4] = { d4.x, d4.y, d4.z, d4.w };
#pragma unroll
        for (int k = 0; k < 4; ++k) {
            if (mtest(msk, dv[k])) {
                int ss = p.src[t * 4 + k];
                unsigned int bit = 1u << (ss & 31);
                unsigned int old = atomicOr(&p.f3m[ss >> 5], bit);
                if (!(old & bit)) AS(&p.agg0[ss], 0.f);
                int q = atomicAdd(p.cntC, 1);
                if (q < CMAX) {
                    unsigned long long ev = (unsigned long long)(unsigned int)ss |
                        ((unsigned long long)(unsigned int)p.pos2[dv[k]] << 32);
                    AS((unsigned long long*)&p.eC[q], ev);
                }
            }
        }
    }
    gsync(p.bar, p.rel, 3);

    // ---- P4: f3[dst] -> agg0[dst] += x[src]  (~65K atomics) ----
    for (int k = tid; k < NMASKW; k += TPB) msk[k] = p.f3m[k];
    __syncthreads();
    {
        const int4* src4 = (const int4*)p.src;
        for (int t = gid; t < NE4; t += T) {
            int4 d4 = dst4[t];
            bool m0 = mtest(msk, d4.x), m1 = mtest(msk, d4.y);
            bool m2 = mtest(msk, d4.z), m3 = mtest(msk, d4.w);
            if (m0 | m1 | m2 | m3) {
                int4 s4 = src4[t];
                if (m0) atomicAdd(&p.agg0[d4.x], p.x[s4.x]);
                if (m1) atomicAdd(&p.agg0[d4.y], p.x[s4.y]);
                if (m2) atomicAdd(&p.agg0[d4.z], p.x[s4.z]);
                if (m3) atomicAdd(&p.agg0[d4.w], p.x[s4.w]);
            }
        }
    }
    gsync(p.bar, p.rel, 4);

    // ---- P5: wave per eC edge: agg1c[slot][j] += lrelu(agg0[src]*W0[j]+b0[j]) ----
    {
        int cC = *p.cntC; if (cC > CMAX) cC = CMAX;
        const int lane = tid & 63;
        const int wid = gid >> 6;
        const float w0 = p.W0[lane], bb0 = p.b0[lane];
        for (int e = wid; e < cC; e += TOTW) {
            int2 ec = p.eC[e];                       // broadcast load
            float x0 = p.agg0[ec.x];                 // broadcast load
            atomicAdd(&p.agg1c[(size_t)ec.y * 64 + lane], lrelu(x0 * w0 + bb0));
        }
    }
    gsync(p.bar, p.rel, 5);

    // ---- P6: layer12 per f2 slot: t2c = lrelu(agg1c@W1+b1)@W2 ----
    {
        int c2 = *p.cnt2; if (c2 > S2MAX) c2 = S2MAX;
        float* rowA = smem;          // 64
        float* rowH = smem + 64;     // 128
        for (int idx = blockIdx.x; idx < c2; idx += GRID) {
            __syncthreads();
            if (tid < 64) rowA[tid] = p.agg1c[(size_t)idx * 64 + tid];
            __syncthreads();
            if (tid < 128) {
                float acc = p.b1[tid];
#pragma unroll
                for (int k = 0; k < 64; ++k) acc += rowA[k] * p.W1[k * 128 + tid];
                rowH[tid] = lrelu(acc);
            }
            __syncthreads();
            if (tid < 64) {
                float a2 = 0.f;
#pragma unroll
                for (int k = 0; k < 128; ++k) a2 += rowH[k] * p.W2[k * 64 + tid];
                AS(&p.t2c[(size_t)idx * 64 + tid], a2);
            }
        }
    }
    gsync(p.bar, p.rel, 6);

    // ---- P7: block-0 tail: layer-3 agg (LDS) + layer-4 + output ----
    if (blockIdx.x != 0) return;
    {
        float* acc = smem;                 // MAXN1*64
        float* t3s = smem + MAXN1 * 64;    // MAXN1
        int c1 = *p.cnt1;  if (c1 > MAXN1) c1 = MAXN1;
        int cD = *p.cntD;  if (cD > DMAX) cD = DMAX;
        int cE = *p.cntE1; if (cE > E1MAX) cE = E1MAX;
        for (int k = tid; k < c1 * 64; k += TPB) acc[k] = 0.f;
        int j = tid & 63, widx = tid >> 6;     // 16 waves
        for (int c0 = 0; c0 < cD; c0 += EDCHUNK) {
            int n = cD - c0; if (n > EDCHUNK) n = EDCHUNK;
            __syncthreads();
            for (int i = tid; i < n; i += TPB) {      // parallel remap: (slot2, slot1)
                int2 e = p.eD[c0 + i];
                eDs[i] = make_int2(p.pos2[e.x], e.y);
            }
            __syncthreads();
            for (int idx = widx; idx < n; idx += NW) {
                int2 e = eDs[idx];
                if (e.y < c1)
                    atomicAdd(&acc[e.y * 64 + j], p.t2c[(size_t)e.x * 64 + j]);
            }
        }
        __syncthreads();
        for (int slot = widx; slot < c1; slot += NW) {
            float v = lrelu(acc[slot * 64 + j] + p.b2[j]) * p.W3[j];
            for (int off = 32; off > 0; off >>= 1) v += __shfl_down(v, off, 64);
            if (j == 0) t3s[slot] = v;
        }
        __syncthreads();
        if (tid < 64) {
            float ssum = 0.f;
            for (int k = tid; k < cE; k += 64) ssum += t3s[p.pos1[p.e1src[k]]];
            for (int off = 32; off > 0; off >>= 1) ssum += __shfl_down(ssum, off, 64);
            if (tid == 0) p.out[0] = lrelu(ssum + p.b3[0]);
        }
    }
}

extern "C" void kernel_launch(void* const* d_in, const int* in_sizes, int n_in,
                              void* d_out, int out_size, void* d_ws, size_t ws_size,
                              hipStream_t stream) {
    Params hp;
    hp.x   = (const float*)d_in[0];
    hp.src = (const int*)d_in[1];
    hp.dst = (const int*)d_in[2];
    hp.W0 = (const float*)d_in[3];  hp.b0 = (const float*)d_in[4];
    hp.W1 = (const float*)d_in[5];  hp.b1 = (const float*)d_in[6];
    hp.W2 = (const float*)d_in[7];  hp.b2 = (const float*)d_in[8];
    hp.W3 = (const float*)d_in[9];  hp.b3 = (const float*)d_in[10];
    hp.out = (float*)d_out;

    char* base = (char*)d_ws;
    size_t off = 0;
    auto take = [&](size_t bytes) { char* q = base + off; off += (bytes + 255) & ~(size_t)255; return q; };
    // ---- zeroed prefix (~21 KB memset); take() pads to 256B so bar/rel get
    //      separate cache lines (arrival RMWs never contend with release spin-reads) ----
    hp.f1m   = (unsigned int*)take(NMASKW * 4);
    hp.f2m   = (unsigned int*)take(NMASKW * 4);
    hp.f3m   = (unsigned int*)take(NMASKW * 4);
    hp.cntE1 = (int*)take(4);
    hp.cntD  = (int*)take(4);
    hp.cntC  = (int*)take(4);
    hp.cnt1  = (int*)take(4);
    hp.cnt2  = (int*)take(4);
    hp.bar   = (int*)take(4);
    hp.rel   = (int*)take(4);
    size_t zero_bytes = off;
    // ---- uninitialized (zeroed on demand) ----
    hp.agg0  = (float*)take((size_t)N_NODES * 4);
    hp.agg1c = (float*)take((size_t)S2MAX * 64 * 4);
    hp.t2c   = (float*)take((size_t)S2MAX * 64 * 4);
    hp.e1src = (int*)take((size_t)E1MAX * 4);
    hp.eD    = (int2*)take((size_t)DMAX * 8);
    hp.eC    = (int2*)take((size_t)CMAX * 8);
    hp.pos1  = (int*)take((size_t)N_NODES * 4);
    hp.pos2  = (int*)take((size_t)N_NODES * 4);

    hipMemsetAsync(base, 0, zero_bytes, stream);     // masks + counters + bar/rel
    gcn_k<<<GRID, TPB, 0, stream>>>(hp);
}

// Round 6
// 177.966 us; speedup vs baseline: 1.6085x; 1.6085x over previous
//
#include <hip/hip_runtime.h>

#define N_NODES 50000
#define N_EDGES 800000
#define NE4 (N_EDGES / 4)
#define NMASKW 1568          // ceil(50000/32)=1563, padded
#define MAXN1 192            // f1 slots (tail LDS acc rows); deg(node1)~16
#define S2MAX 1024           // f2 slot cap (actual ~254)
#define DMAX  4096           // eD cap (actual ~256)
#define CMAX  16384          // eC cap (actual ~4096)
#define E1MAX 1024           // e1src cap (actual ~16)
#define SB   ((NE4 + 255) / 256)   // 782 scan blocks

// Cross-dispatch non-atomic WRITES: write-through to the coherence point (no
// L2-resident dirty lines). Cross-dispatch READS are plain cached — safe via
// dispatch-boundary acquire. Within K5, t2c is AS-written, drained (the
// __syncthreads vmcnt(0)) before the done-increment, and never plain-read
// before the tail -> tail's cached reads are coherent.
#define AS(p, v) __hip_atomic_store((p), (v), __ATOMIC_RELAXED, __HIP_MEMORY_SCOPE_AGENT)

__device__ __forceinline__ float lrelu(float v) { return v >= 0.f ? v : 0.01f * v; }
__device__ __forceinline__ bool mtest(const unsigned int* m, int i) {
    return (m[i >> 5] >> (i & 31)) & 1u;
}

// ---- K1: dst==1 -> e1src list, f1 bit, pos1 slot ----
__global__ __launch_bounds__(256) void scan1_k(const int4* __restrict__ dst4,
                                               const int* __restrict__ src,
                                               unsigned int* __restrict__ f1m,
                                               int* __restrict__ e1src, int* __restrict__ cntE1,
                                               int* __restrict__ pos1, int* __restrict__ cnt1) {
    int t = blockIdx.x * 256 + threadIdx.x;
    if (t >= NE4) return;
    int4 d4 = dst4[t];
#define E1(dd, off) \
    if (dd == 1) { \
        int ss = src[t * 4 + off]; \
        int q = atomicAdd(cntE1, 1); \
        if (q < E1MAX) AS(&e1src[q], ss); \
        unsigned int bit = 1u << (ss & 31); \
        unsigned int old = atomicOr(&f1m[ss >> 5], bit); \
        if (!(old & bit)) { int q1 = atomicAdd(cnt1, 1); AS(&pos1[ss], q1); } }
    E1(d4.x, 0) E1(d4.y, 1) E1(d4.z, 2) E1(d4.w, 3)
#undef E1
}

// ---- K2: f1[dst] -> eD=(src, pos1[dst]); f2 first-setter -> pos2 slot ----
__global__ __launch_bounds__(256) void scan2_k(const int4* __restrict__ dst4,
                                               const int* __restrict__ src,
                                               const unsigned int* __restrict__ f1m,
                                               unsigned int* __restrict__ f2m,
                                               const int* __restrict__ pos1,
                                               int* __restrict__ pos2, int* __restrict__ cnt2,
                                               int2* __restrict__ eD, int* __restrict__ cntD) {
    __shared__ unsigned int msk[NMASKW];
    for (int k = threadIdx.x; k < NMASKW; k += 256) msk[k] = f1m[k];
    __syncthreads();
    int t = blockIdx.x * 256 + threadIdx.x;
    if (t >= NE4) return;
    int4 d4 = dst4[t];
#define E2(dd, off) \
    if (mtest(msk, dd)) { \
        int ss = src[t * 4 + off]; \
        unsigned int bit = 1u << (ss & 31); \
        unsigned int old = atomicOr(&f2m[ss >> 5], bit); \
        if (!(old & bit)) { int q2 = atomicAdd(cnt2, 1); if (q2 < S2MAX) AS(&pos2[ss], q2); } \
        int q = atomicAdd(cntD, 1); \
        if (q < DMAX) { \
            unsigned long long ev = (unsigned long long)(unsigned int)ss | \
                ((unsigned long long)(unsigned int)pos1[dd] << 32); \
            AS((unsigned long long*)&eD[q], ev); } }
    E2(d4.x, 0) E2(d4.y, 1) E2(d4.z, 2) E2(d4.w, 3)
#undef E2
}

// ---- K3: f2[dst] -> eC=(src, pos2[dst]); f3 first-setter -> zero agg0[src] ----
__global__ __launch_bounds__(256) void scan3_k(const int4* __restrict__ dst4,
                                               const int* __restrict__ src,
                                               const unsigned int* __restrict__ f2m,
                                               unsigned int* __restrict__ f3m,
                                               const int* __restrict__ pos2,
                                               float* __restrict__ agg0,
                                               int2* __restrict__ eC, int* __restrict__ cntC) {
    __shared__ unsigned int msk[NMASKW];
    for (int k = threadIdx.x; k < NMASKW; k += 256) msk[k] = f2m[k];
    __syncthreads();
    int t = blockIdx.x * 256 + threadIdx.x;
    if (t >= NE4) return;
    int4 d4 = dst4[t];
#define E3(dd, off) \
    if (mtest(msk, dd)) { \
        int ss = src[t * 4 + off]; \
        unsigned int bit = 1u << (ss & 31); \
        unsigned int old = atomicOr(&f3m[ss >> 5], bit); \
        if (!(old & bit)) AS(&agg0[ss], 0.f); \
        int q = atomicAdd(cntC, 1); \
        if (q < CMAX) { \
            unsigned long long ev = (unsigned long long)(unsigned int)ss | \
                ((unsigned long long)(unsigned int)pos2[dd] << 32); \
            AS((unsigned long long*)&eC[q], ev); } }
    E3(d4.x, 0) E3(d4.y, 1) E3(d4.z, 2) E3(d4.w, 3)
#undef E3
}

// ---- K4: f3[dst] -> agg0[dst] += x[src]  (~65K atomics) ----
__global__ __launch_bounds__(256) void scan4_k(const int4* __restrict__ dst4,
                                               const int4* __restrict__ src4,
                                               const float* __restrict__ x,
                                               const unsigned int* __restrict__ f3m,
                                               float* __restrict__ agg0) {
    __shared__ unsigned int msk[NMASKW];
    for (int k = threadIdx.x; k < NMASKW; k += 256) msk[k] = f3m[k];
    __syncthreads();
    int t = blockIdx.x * 256 + threadIdx.x;
    if (t >= NE4) return;
    int4 d4 = dst4[t];
    bool m0 = mtest(msk, d4.x), m1 = mtest(msk, d4.y);
    bool m2 = mtest(msk, d4.z), m3 = mtest(msk, d4.w);
    if (m0 | m1 | m2 | m3) {
        int4 s4 = src4[t];
        if (m0) atomicAdd(&agg0[d4.x], x[s4.x]);
        if (m1) atomicAdd(&agg0[d4.y], x[s4.y]);
        if (m2) atomicAdd(&agg0[d4.z], x[s4.z]);
        if (m3) atomicAdd(&agg0[d4.w], x[s4.w]);
    }
}

// ---- K5: block per f2-slot: gather row from eC (no atomics) + per-row GEMM
//          64->128->64 -> t2c[slot]; done-counter; last block runs fused tail ----
struct P5 {
    const int2* eC; const int* cntC; const float* agg0;
    const float* W0; const float* b0; const float* W1; const float* b1;
    const float* W2; const float* b2; const float* W3; const float* b3;
    const int* cnt2; const int* pos1; const int* pos2;
    const int2* eD; const int* cntD; const int* e1src; const int* cntE1;
    const int* cnt1; float* t2c; int* done; float* out;
};

__global__ __launch_bounds__(256) void fused5_k(P5 p) {
    __shared__ __align__(16) float smem[MAXN1 * 64 + MAXN1];   // 49.9 KB (tail acc + t3s)
    __shared__ int midx[256];
    __shared__ int mcnt;
    __shared__ int lflag;
    const int tid = threadIdx.x;
    const int b = blockIdx.x;
    int c2 = *p.cnt2; if (c2 > S2MAX) c2 = S2MAX;

    if (b < c2) {
        // -- gather row b: racc[j] = sum over eC edges with slot==b of lrelu(agg0[src]*W0[j]+b0[j])
        int cC = *p.cntC; if (cC > CMAX) cC = CMAX;
        const int eg = tid >> 6, j = tid & 63;          // 4 entry-groups x 64 lanes
        const float w0 = p.W0[j], bb0 = p.b0[j];
        float racc = 0.f;
        for (int base = 0; base < cC; base += 256) {
            if (tid == 0) mcnt = 0;
            __syncthreads();
            int i = base + tid;
            if (i < cC) {
                int2 e = p.eC[i];
                if (e.y == b) midx[atomicAdd(&mcnt, 1)] = e.x;
            }
            __syncthreads();
            int nm = mcnt;
            for (int m = eg; m < nm; m += 4) {
                float x0 = p.agg0[midx[m]];              // broadcast load
                racc += lrelu(x0 * w0 + bb0);
            }
            __syncthreads();
        }
        smem[tid] = racc;                                // rowP[4][64]
        __syncthreads();
        if (tid < 64)                                    // rowA[j] = reduce 4 partials
            smem[256 + tid] = smem[tid] + smem[64 + tid] + smem[128 + tid] + smem[192 + tid];
        __syncthreads();
        {
            const float* rowA = smem + 256;
            float* rowH = smem + 320;
            if (tid < 128) {
                float h = p.b1[tid];
#pragma unroll
                for (int k = 0; k < 64; ++k) h += rowA[k] * p.W1[k * 128 + tid];
                rowH[tid] = lrelu(h);
            }
            __syncthreads();
            if (tid < 64) {
                float a2 = 0.f;
#pragma unroll
                for (int k = 0; k < 128; ++k) a2 += rowH[k] * p.W2[k * 64 + tid];
                AS(&p.t2c[(size_t)b * 64 + tid], a2);
            }
        }
    }

    // -- done-counter: __syncthreads drains this block's AS stores (vmcnt 0),
    //    then one increment; the last block (sees gridDim-1) runs the tail.
    __syncthreads();
    if (tid == 0) {
        int old = __hip_atomic_fetch_add(p.done, 1, __ATOMIC_RELAXED, __HIP_MEMORY_SCOPE_AGENT);
        lflag = (old == (int)gridDim.x - 1);
    }
    __syncthreads();
    if (!lflag) return;

    // ---- fused tail: layer-3 agg (LDS) + layer-4 + output ----
    {
        float* acc = smem;                 // MAXN1*64
        float* t3s = smem + MAXN1 * 64;    // MAXN1
        int c1 = *p.cnt1;  if (c1 > MAXN1) c1 = MAXN1;
        int cD = *p.cntD;  if (cD > DMAX) cD = DMAX;
        int cE = *p.cntE1; if (cE > E1MAX) cE = E1MAX;
        for (int k = tid; k < c1 * 64; k += 256) acc[k] = 0.f;
        __syncthreads();
        int j = tid & 63, widx = tid >> 6;     // 4 waves
        for (int idx = widx; idx < cD; idx += 4) {
            int2 e = p.eD[idx];                            // (src, slot1)
            int s2 = p.pos2[e.x];
            if (e.y < c1 && (unsigned)s2 < (unsigned)c2)
                atomicAdd(&acc[e.y * 64 + j], p.t2c[(size_t)s2 * 64 + j]);
        }
        __syncthreads();
        for (int slot = widx; slot < c1; slot += 4) {
            float v = lrelu(acc[slot * 64 + j] + p.b2[j]) * p.W3[j];
            for (int off = 32; off > 0; off >>= 1) v += __shfl_down(v, off, 64);
            if (j == 0) t3s[slot] = v;
        }
        __syncthreads();
        if (tid < 64) {
            float ssum = 0.f;
            for (int k = tid; k < cE; k += 64) ssum += t3s[p.pos1[p.e1src[k]]];
            for (int off = 32; off > 0; off >>= 1) ssum += __shfl_down(ssum, off, 64);
            if (tid == 0) p.out[0] = lrelu(ssum + p.b3[0]);
        }
    }
}

extern "C" void kernel_launch(void* const* d_in, const int* in_sizes, int n_in,
                              void* d_out, int out_size, void* d_ws, size_t ws_size,
                              hipStream_t stream) {
    const float* x   = (const float*)d_in[0];
    const int*   src = (const int*)d_in[1];
    const int*   dst = (const int*)d_in[2];
    const float* W0 = (const float*)d_in[3];  const float* b0 = (const float*)d_in[4];
    const float* W1 = (const float*)d_in[5];  const float* b1 = (const float*)d_in[6];
    const float* W2 = (const float*)d_in[7];  const float* b2 = (const float*)d_in[8];
    const float* W3 = (const float*)d_in[9];  const float* b3 = (const float*)d_in[10];
    float* out = (float*)d_out;
    const int4* dst4 = (const int4*)dst;
    const int4* src4 = (const int4*)src;

    char* base = (char*)d_ws;
    size_t off = 0;
    auto take = [&](size_t bytes) { char* q = base + off; off += (bytes + 255) & ~(size_t)255; return q; };
    // ---- zeroed prefix (~21 KB memset) ----
    unsigned int* f1m = (unsigned int*)take(NMASKW * 4);
    unsigned int* f2m = (unsigned int*)take(NMASKW * 4);
    unsigned int* f3m = (unsigned int*)take(NMASKW * 4);
    int* cntE1 = (int*)take(4);
    int* cntD  = (int*)take(4);
    int* cntC  = (int*)take(4);
    int* cnt1  = (int*)take(4);
    int* cnt2  = (int*)take(4);
    int* done  = (int*)take(4);
    size_t zero_bytes = off;
    // ---- uninitialized (written before read) ----
    float* agg0  = (float*)take((size_t)N_NODES * 4);
    float* t2c   = (float*)take((size_t)S2MAX * 64 * 4);
    int*   e1src = (int*)take((size_t)E1MAX * 4);
    int2*  eD    = (int2*)take((size_t)DMAX * 8);
    int2*  eC    = (int2*)take((size_t)CMAX * 8);
    int*   pos1  = (int*)take((size_t)N_NODES * 4);
    int*   pos2  = (int*)take((size_t)N_NODES * 4);

    hipMemsetAsync(base, 0, zero_bytes, stream);     // masks + counters + done

    scan1_k<<<SB, 256, 0, stream>>>(dst4, src, f1m, e1src, cntE1, pos1, cnt1);
    scan2_k<<<SB, 256, 0, stream>>>(dst4, src, f1m, f2m, pos1, pos2, cnt2, eD, cntD);
    scan3_k<<<SB, 256, 0, stream>>>(dst4, src, f2m, f3m, pos2, agg0, eC, cntC);
    scan4_k<<<SB, 256, 0, stream>>>(dst4, src4, x, f3m, agg0);

    P5 hp;
    hp.eC = eC; hp.cntC = cntC; hp.agg0 = agg0;
    hp.W0 = W0; hp.b0 = b0; hp.W1 = W1; hp.b1 = b1;
    hp.W2 = W2; hp.b2 = b2; hp.W3 = W3; hp.b3 = b3;
    hp.cnt2 = cnt2; hp.pos1 = pos1; hp.pos2 = pos2;
    hp.eD = eD; hp.cntD = cntD; hp.e1src = e1src; hp.cntE1 = cntE1;
    hp.cnt1 = cnt1; hp.t2c = t2c; hp.done = done; hp.out = out;
    fused5_k<<<S2MAX, 256, 0, stream>>>(hp);
}

// Round 8
// 156.033 us; speedup vs baseline: 1.8346x; 1.1406x over previous
//
#include <hip/hip_runtime.h>

#define N_NODES 50000
#define N_EDGES 800000
#define NE4 (N_EDGES / 4)
#define NMASKW 1568          // ceil(50000/32)=1563, padded
#define MAXN1 192            // f1 slots (tail LDS acc rows); deg(node1)~16
#define S2MAX 1024           // f2 slot cap (actual ~254)
#define DMAX  4096           // eD cap (actual ~256)
#define E1MAX 1024           // e1src cap (actual ~16)
#define BK    96             // per-f2-slot bucket capacity (in-deg ~Poisson(16))
#define SB   ((NE4 + 255) / 256)   // 782 scan blocks
#define FGRID 256            // fused kernel grid (one scheduling wave)
#define SUBN 8               // hierarchical done: 8 sub-counters
#define SUBW 64              // sub-counter stride in ints (256B apart)

// Cross-dispatch non-atomic WRITES: write-through to the coherence point.
// Cross-dispatch READS: plain cached (dispatch-start acquire invalidates L2).
// Within fused6: t2c is AS-written (bypasses L2), drained by __syncthreads
// before the done arrival, and first plain-read by the tail -> L2 miss -> MALL.
#define AS(p, v) __hip_atomic_store((p), (v), __ATOMIC_RELAXED, __HIP_MEMORY_SCOPE_AGENT)

__device__ __forceinline__ float lrelu(float v) { return v >= 0.f ? v : 0.01f * v; }
__device__ __forceinline__ bool mtest(const unsigned int* m, int i) {
    return (m[i >> 5] >> (i & 31)) & 1u;
}

// ---- K1: dst==1 -> e1src list, f1 bit, pos1 slot ----
__global__ __launch_bounds__(256) void scan1_k(const int4* __restrict__ dst4,
                                               const int* __restrict__ src,
                                               unsigned int* __restrict__ f1m,
                                               int* __restrict__ e1src, int* __restrict__ cntE1,
                                               int* __restrict__ pos1, int* __restrict__ cnt1) {
    int t = blockIdx.x * 256 + threadIdx.x;
    if (t >= NE4) return;
    int4 d4 = dst4[t];
#define E1(dd, off) \
    if (dd == 1) { \
        int ss = src[t * 4 + off]; \
        int q = atomicAdd(cntE1, 1); \
        if (q < E1MAX) AS(&e1src[q], ss); \
        unsigned int bit = 1u << (ss & 31); \
        unsigned int old = atomicOr(&f1m[ss >> 5], bit); \
        if (!(old & bit)) { int q1 = atomicAdd(cnt1, 1); AS(&pos1[ss], q1); } }
    E1(d4.x, 0) E1(d4.y, 1) E1(d4.z, 2) E1(d4.w, 3)
#undef E1
}

// ---- K2: f1[dst] -> eD=(src, pos1[dst]); f2 first-setter -> pos2 slot ----
__global__ __launch_bounds__(256) void scan2_k(const int4* __restrict__ dst4,
                                               const int* __restrict__ src,
                                               const unsigned int* __restrict__ f1m,
                                               unsigned int* __restrict__ f2m,
                                               const int* __restrict__ pos1,
                                               int* __restrict__ pos2, int* __restrict__ cnt2,
                                               int2* __restrict__ eD, int* __restrict__ cntD) {
    __shared__ unsigned int msk[NMASKW];
    for (int k = threadIdx.x; k < NMASKW; k += 256) msk[k] = f1m[k];
    __syncthreads();
    int t = blockIdx.x * 256 + threadIdx.x;
    if (t >= NE4) return;
    int4 d4 = dst4[t];
#define E2(dd, off) \
    if (mtest(msk, dd)) { \
        int ss = src[t * 4 + off]; \
        unsigned int bit = 1u << (ss & 31); \
        unsigned int old = atomicOr(&f2m[ss >> 5], bit); \
        if (!(old & bit)) { int q2 = atomicAdd(cnt2, 1); if (q2 < S2MAX) AS(&pos2[ss], q2); } \
        int q = atomicAdd(cntD, 1); \
        if (q < DMAX) { \
            unsigned long long ev = (unsigned long long)(unsigned int)ss | \
                ((unsigned long long)(unsigned int)pos1[dd] << 32); \
            AS((unsigned long long*)&eD[q], ev); } }
    E2(d4.x, 0) E2(d4.y, 1) E2(d4.z, 2) E2(d4.w, 3)
#undef E2
}

// ---- K3: f2[dst] -> bucket[pos2[dst]] += src; f3 first-setter -> zero agg0[src] ----
__global__ __launch_bounds__(256) void scan3_k(const int4* __restrict__ dst4,
                                               const int* __restrict__ src,
                                               const unsigned int* __restrict__ f2m,
                                               unsigned int* __restrict__ f3m,
                                               const int* __restrict__ pos2,
                                               float* __restrict__ agg0,
                                               int* __restrict__ bucket,
                                               int* __restrict__ slotCnt) {
    __shared__ unsigned int msk[NMASKW];
    for (int k = threadIdx.x; k < NMASKW; k += 256) msk[k] = f2m[k];
    __syncthreads();
    int t = blockIdx.x * 256 + threadIdx.x;
    if (t >= NE4) return;
    int4 d4 = dst4[t];
#define E3(dd, off) \
    if (mtest(msk, dd)) { \
        int ss = src[t * 4 + off]; \
        unsigned int bit = 1u << (ss & 31); \
        unsigned int old = atomicOr(&f3m[ss >> 5], bit); \
        if (!(old & bit)) AS(&agg0[ss], 0.f); \
        int sl = pos2[dd]; \
        if ((unsigned)sl < S2MAX) { \
            int bi = atomicAdd(&slotCnt[sl], 1); \
            if (bi < BK) AS(&bucket[sl * BK + bi], ss); } }
    E3(d4.x, 0) E3(d4.y, 1) E3(d4.z, 2) E3(d4.w, 3)
#undef E3
}

// ---- K4: f3[dst] -> agg0[dst] += x[src]  (~65K atomics) ----
__global__ __launch_bounds__(256) void scan4_k(const int4* __restrict__ dst4,
                                               const int4* __restrict__ src4,
                                               const float* __restrict__ x,
                                               const unsigned int* __restrict__ f3m,
                                               float* __restrict__ agg0) {
    __shared__ unsigned int msk[NMASKW];
    for (int k = threadIdx.x; k < NMASKW; k += 256) msk[k] = f3m[k];
    __syncthreads();
    int t = blockIdx.x * 256 + threadIdx.x;
    if (t >= NE4) return;
    int4 d4 = dst4[t];
    bool m0 = mtest(msk, d4.x), m1 = mtest(msk, d4.y);
    bool m2 = mtest(msk, d4.z), m3 = mtest(msk, d4.w);
    if (m0 | m1 | m2 | m3) {
        int4 s4 = src4[t];
        if (m0) atomicAdd(&agg0[d4.x], x[s4.x]);
        if (m1) atomicAdd(&agg0[d4.y], x[s4.y]);
        if (m2) atomicAdd(&agg0[d4.z], x[s4.z]);
        if (m3) atomicAdd(&agg0[d4.w], x[s4.w]);
    }
}

// ---- K5: block per f2-slot (bucket-indexed, no eC scan): row gather + GEMM
//          64->128->64 -> t2c; hierarchical done; last block runs fused tail ----
struct P6 {
    const int* bucket; const int* slotCnt; const float* agg0;
    const float* W0; const float* b0; const float* W1; const float* b1;
    const float* W2; const float* b2; const float* W3; const float* b3;
    const int* cnt2; const int* pos1; const int* pos2;
    const int2* eD; const int* cntD; const int* e1src; const int* cntE1;
    const int* cnt1; float* t2c; int* sub; int* top; float* out;
};

__global__ __launch_bounds__(256) void fused6_k(P6 p) {
    __shared__ __align__(16) float smem[MAXN1 * 64 + MAXN1];   // 49,920 B
    __shared__ int lflag;
    const int tid = threadIdx.x;
    int c2 = *p.cnt2; if (c2 > S2MAX) c2 = S2MAX;

    // rowgemm scratch carved from smem (reused by the tail afterwards)
    float* xv   = smem;          // [BK]   agg0 values of bucket srcs
    float* part = smem + 128;    // [256]  4x64 partial sums
    float* rowA = smem + 384;    // [64]
    float* rowH = smem + 448;    // [128]

    const int g = tid >> 6, j = tid & 63;
    const float w0 = p.W0[j], bb0 = p.b0[j];

    for (int b = blockIdx.x; b < c2; b += FGRID) {
        int cnt = p.slotCnt[b]; if (cnt > BK) cnt = BK;
        if (tid < cnt) xv[tid] = p.agg0[p.bucket[b * BK + tid]];   // parallel gather
        __syncthreads();
        float racc = 0.f;
        for (int m = g; m < cnt; m += 4) racc += lrelu(xv[m] * w0 + bb0);
        part[tid] = racc;
        __syncthreads();
        if (tid < 64)
            rowA[tid] = part[tid] + part[64 + tid] + part[128 + tid] + part[192 + tid];
        __syncthreads();
        if (tid < 128) {
            float h = p.b1[tid];
#pragma unroll
            for (int k = 0; k < 64; ++k) h += rowA[k] * p.W1[k * 128 + tid];
            rowH[tid] = lrelu(h);
        }
        __syncthreads();
        if (tid < 64) {
            float a2 = 0.f;
#pragma unroll
            for (int k = 0; k < 128; ++k) a2 += rowH[k] * p.W2[k * 64 + tid];
            AS(&p.t2c[(size_t)b * 64 + tid], a2);
        }
        __syncthreads();          // protect xv/part before next slot
    }

    // -- hierarchical done: __syncthreads (drains this block's AS stores) ->
    //    sub-counter (32 arrivals each, separate lines) -> top (8 arrivals).
    __syncthreads();
    if (tid == 0) {
        lflag = 0;
        int s = blockIdx.x & (SUBN - 1);
        int old = __hip_atomic_fetch_add(&p.sub[s * SUBW], 1,
                                         __ATOMIC_RELAXED, __HIP_MEMORY_SCOPE_AGENT);
        if (old == (FGRID / SUBN) - 1) {
            int o2 = __hip_atomic_fetch_add(p.top, 1,
                                            __ATOMIC_RELAXED, __HIP_MEMORY_SCOPE_AGENT);
            lflag = (o2 == SUBN - 1);
        }
    }
    __syncthreads();
    if (!lflag) return;

    // ---- fused tail: layer-3 agg (LDS) + layer-4 + output ----
    {
        float* acc = smem;                 // MAXN1*64
        float* t3s = smem + MAXN1 * 64;    // MAXN1
        int c1 = *p.cnt1;  if (c1 > MAXN1) c1 = MAXN1;
        int cD = *p.cntD;  if (cD > DMAX) cD = DMAX;
        int cE = *p.cntE1; if (cE > E1MAX) cE = E1MAX;
        for (int k = tid; k < c1 * 64; k += 256) acc[k] = 0.f;
        __syncthreads();
        int widx = tid >> 6;                   // 4 waves, j = lane
        for (int idx = widx; idx < cD; idx += 4) {
            int2 e = p.eD[idx];                            // (src, slot1)
            int s2 = p.pos2[e.x];
            if (e.y < c1 && (unsigned)s2 < (unsigned)c2)
                atomicAdd(&acc[e.y * 64 + j], p.t2c[(size_t)s2 * 64 + j]);
        }
        __syncthreads();
        for (int slot = widx; slot < c1; slot += 4) {
            float v = lrelu(acc[slot * 64 + j] + p.b2[j]) * p.W3[j];
            for (int off = 32; off > 0; off >>= 1) v += __shfl_down(v, off, 64);
            if (j == 0) t3s[slot] = v;
        }
        __syncthreads();
        if (tid < 64) {
            float ssum = 0.f;
            for (int k = tid; k < cE; k += 64) ssum += t3s[p.pos1[p.e1src[k]]];
            for (int off = 32; off > 0; off >>= 1) ssum += __shfl_down(ssum, off, 64);
            if (tid == 0) p.out[0] = lrelu(ssum + p.b3[0]);
        }
    }
}

extern "C" void kernel_launch(void* const* d_in, const int* in_sizes, int n_in,
                              void* d_out, int out_size, void* d_ws, size_t ws_size,
                              hipStream_t stream) {
    const float* x   = (const float*)d_in[0];
    const int*   src = (const int*)d_in[1];
    const int*   dst = (const int*)d_in[2];
    const float* W0 = (const float*)d_in[3];  const float* b0 = (const float*)d_in[4];
    const float* W1 = (const float*)d_in[5];  const float* b1 = (const float*)d_in[6];
    const float* W2 = (const float*)d_in[7];  const float* b2 = (const float*)d_in[8];
    const float* W3 = (const float*)d_in[9];  const float* b3 = (const float*)d_in[10];
    float* out = (float*)d_out;
    const int4* dst4 = (const int4*)dst;
    const int4* src4 = (const int4*)src;

    char* base = (char*)d_ws;
    size_t off = 0;
    auto take = [&](size_t bytes) { char* q = base + off; off += (bytes + 255) & ~(size_t)255; return q; };
    // ---- zeroed prefix (~28 KB memset) ----
    unsigned int* f1m = (unsigned int*)take(NMASKW * 4);
    unsigned int* f2m = (unsigned int*)take(NMASKW * 4);
    unsigned int* f3m = (unsigned int*)take(NMASKW * 4);
    int* cntE1 = (int*)take(4);
    int* cntD  = (int*)take(4);
    int* cnt1  = (int*)take(4);
    int* cnt2  = (int*)take(4);
    int* slotCnt = (int*)take((size_t)S2MAX * 4);
    int* sub   = (int*)take((size_t)SUBN * SUBW * 4);   // 8 counters, 256B apart
    int* top   = (int*)take(4);
    size_t zero_bytes = off;
    // ---- uninitialized (written before read) ----
    float* agg0   = (float*)take((size_t)N_NODES * 4);
    float* t2c    = (float*)take((size_t)S2MAX * 64 * 4);
    int*   e1src  = (int*)take((size_t)E1MAX * 4);
    int2*  eD     = (int2*)take((size_t)DMAX * 8);
    int*   bucket = (int*)take((size_t)S2MAX * BK * 4);
    int*   pos1   = (int*)take((size_t)N_NODES * 4);
    int*   pos2   = (int*)take((size_t)N_NODES * 4);

    hipMemsetAsync(base, 0, zero_bytes, stream);

    scan1_k<<<SB, 256, 0, stream>>>(dst4, src, f1m, e1src, cntE1, pos1, cnt1);
    scan2_k<<<SB, 256, 0, stream>>>(dst4, src, f1m, f2m, pos1, pos2, cnt2, eD, cntD);
    scan3_k<<<SB, 256, 0, stream>>>(dst4, src, f2m, f3m, pos2, agg0, bucket, slotCnt);
    scan4_k<<<SB, 256, 0, stream>>>(dst4, src4, x, f3m, agg0);

    P6 hp;
    hp.bucket = bucket; hp.slotCnt = slotCnt; hp.agg0 = agg0;
    hp.W0 = W0; hp.b0 = b0; hp.W1 = W1; hp.b1 = b1;
    hp.W2 = W2; hp.b2 = b2; hp.W3 = W3; hp.b3 = b3;
    hp.cnt2 = cnt2; hp.pos1 = pos1; hp.pos2 = pos2;
    hp.eD = eD; hp.cntD = cntD; hp.e1src = e1src; hp.cntE1 = cntE1;
    hp.cnt1 = cnt1; hp.t2c = t2c; hp.sub = sub; hp.top = top; hp.out = out;
    fused6_k<<<FGRID, 256, 0, stream>>>(hp);
}

// Round 9
// 128.772 us; speedup vs baseline: 2.2230x; 1.2117x over previous
//
#include <hip/hip_runtime.h>

#define N_NODES 50000
#define N_EDGES 800000
#define NE4 (N_EDGES / 4)
#define NMASKW 1568          // ceil(50000/32)=1563, padded
#define MAXN1 192            // f1 slots; deg(node1)~16
#define S2MAX 1024           // f2 slot cap (actual ~254)
#define DMAX  4096           // eD cap (actual ~256)
#define E1MAX 1024           // e1src cap (actual ~16)
#define BK    96             // per-f2-slot bucket capacity (in-deg ~Poisson(16))
#define SB   ((NE4 + 255) / 256)   // 782 scan blocks
#define FGRID 256            // fused kernel grid (one scheduling wave)
#define SUBN 8               // hierarchical done: 8 sub-counters
#define SUBW 64              // sub-counter stride in ints (256B apart)

// Cross-dispatch non-atomic WRITES: write-through to the coherence point.
// Cross-dispatch READS: plain cached (dispatch-start acquire invalidates L2).
// Within fused7: gacc is atomically written (coherence point), drained by the
// __syncthreads before the done arrival, and first plain-read by the tail.
#define AS(p, v) __hip_atomic_store((p), (v), __ATOMIC_RELAXED, __HIP_MEMORY_SCOPE_AGENT)

__device__ __forceinline__ float lrelu(float v) { return v >= 0.f ? v : 0.01f * v; }
__device__ __forceinline__ bool mtest(const unsigned int* m, int i) {
    return (m[i >> 5] >> (i & 31)) & 1u;
}

// ---- K1: dst==1 -> e1src list, f1 bit, pos1 slot ----
__global__ __launch_bounds__(256) void scan1_k(const int4* __restrict__ dst4,
                                               const int* __restrict__ src,
                                               unsigned int* __restrict__ f1m,
                                               int* __restrict__ e1src, int* __restrict__ cntE1,
                                               int* __restrict__ pos1, int* __restrict__ cnt1) {
    int t = blockIdx.x * 256 + threadIdx.x;
    if (t >= NE4) return;
    int4 d4 = dst4[t];
#define E1(dd, off) \
    if (dd == 1) { \
        int ss = src[t * 4 + off]; \
        int q = atomicAdd(cntE1, 1); \
        if (q < E1MAX) AS(&e1src[q], ss); \
        unsigned int bit = 1u << (ss & 31); \
        unsigned int old = atomicOr(&f1m[ss >> 5], bit); \
        if (!(old & bit)) { int q1 = atomicAdd(cnt1, 1); AS(&pos1[ss], q1); } }
    E1(d4.x, 0) E1(d4.y, 1) E1(d4.z, 2) E1(d4.w, 3)
#undef E1
}

// ---- K2: f1[dst] -> eD=(src, pos1[dst]); f2 first-setter -> pos2 slot ----
__global__ __launch_bounds__(256) void scan2_k(const int4* __restrict__ dst4,
                                               const int* __restrict__ src,
                                               const unsigned int* __restrict__ f1m,
                                               unsigned int* __restrict__ f2m,
                                               const int* __restrict__ pos1,
                                               int* __restrict__ pos2, int* __restrict__ cnt2,
                                               int2* __restrict__ eD, int* __restrict__ cntD) {
    __shared__ unsigned int msk[NMASKW];
    for (int k = threadIdx.x; k < NMASKW; k += 256) msk[k] = f1m[k];
    __syncthreads();
    int t = blockIdx.x * 256 + threadIdx.x;
    if (t >= NE4) return;
    int4 d4 = dst4[t];
#define E2(dd, off) \
    if (mtest(msk, dd)) { \
        int ss = src[t * 4 + off]; \
        unsigned int bit = 1u << (ss & 31); \
        unsigned int old = atomicOr(&f2m[ss >> 5], bit); \
        if (!(old & bit)) { int q2 = atomicAdd(cnt2, 1); if (q2 < S2MAX) AS(&pos2[ss], q2); } \
        int q = atomicAdd(cntD, 1); \
        if (q < DMAX) { \
            unsigned long long ev = (unsigned long long)(unsigned int)ss | \
                ((unsigned long long)(unsigned int)pos1[dd] << 32); \
            AS((unsigned long long*)&eD[q], ev); } }
    E2(d4.x, 0) E2(d4.y, 1) E2(d4.z, 2) E2(d4.w, 3)
#undef E2
}

// ---- K3: f2[dst] -> bucket[pos2[dst]] += src; f3 first-setter -> zero agg0[src] ----
__global__ __launch_bounds__(256) void scan3_k(const int4* __restrict__ dst4,
                                               const int* __restrict__ src,
                                               const unsigned int* __restrict__ f2m,
                                               unsigned int* __restrict__ f3m,
                                               const int* __restrict__ pos2,
                                               float* __restrict__ agg0,
                                               int* __restrict__ bucket,
                                               int* __restrict__ slotCnt) {
    __shared__ unsigned int msk[NMASKW];
    for (int k = threadIdx.x; k < NMASKW; k += 256) msk[k] = f2m[k];
    __syncthreads();
    int t = blockIdx.x * 256 + threadIdx.x;
    if (t >= NE4) return;
    int4 d4 = dst4[t];
#define E3(dd, off) \
    if (mtest(msk, dd)) { \
        int ss = src[t * 4 + off]; \
        unsigned int bit = 1u << (ss & 31); \
        unsigned int old = atomicOr(&f3m[ss >> 5], bit); \
        if (!(old & bit)) AS(&agg0[ss], 0.f); \
        int sl = pos2[dd]; \
        if ((unsigned)sl < S2MAX) { \
            int bi = atomicAdd(&slotCnt[sl], 1); \
            if (bi < BK) AS(&bucket[sl * BK + bi], ss); } }
    E3(d4.x, 0) E3(d4.y, 1) E3(d4.z, 2) E3(d4.w, 3)
#undef E3
}

// ---- K4: f3[dst] -> agg0[dst] += x[src]; plus eDr remap (pos2 complete now) ----
__global__ __launch_bounds__(256) void scan4_k(const int4* __restrict__ dst4,
                                               const int4* __restrict__ src4,
                                               const float* __restrict__ x,
                                               const unsigned int* __restrict__ f3m,
                                               float* __restrict__ agg0,
                                               const int2* __restrict__ eD,
                                               const int* __restrict__ cntD,
                                               const int* __restrict__ pos2,
                                               int2* __restrict__ eDr) {
    __shared__ unsigned int msk[NMASKW];
    int g = blockIdx.x * 256 + threadIdx.x;
    {   // eDr[i] = (slot2(src), slot1) — parallel remap of the tiny eD list
        int cD = *cntD; if (cD > DMAX) cD = DMAX;
        if (g < cD) {
            int2 e = eD[g];
            int sl = pos2[e.x];
            unsigned long long ev =
                (unsigned long long)(unsigned int)((unsigned)sl < S2MAX ? sl : -1) |
                ((unsigned long long)(unsigned int)e.y << 32);
            AS((unsigned long long*)&eDr[g], ev);
        }
    }
    for (int k = threadIdx.x; k < NMASKW; k += 256) msk[k] = f3m[k];
    __syncthreads();
    int t = g;
    if (t >= NE4) return;
    int4 d4 = dst4[t];
    bool m0 = mtest(msk, d4.x), m1 = mtest(msk, d4.y);
    bool m2 = mtest(msk, d4.z), m3 = mtest(msk, d4.w);
    if (m0 | m1 | m2 | m3) {
        int4 s4 = src4[t];
        if (m0) atomicAdd(&agg0[d4.x], x[s4.x]);
        if (m1) atomicAdd(&agg0[d4.y], x[s4.y]);
        if (m2) atomicAdd(&agg0[d4.z], x[s4.z]);
        if (m3) atomicAdd(&agg0[d4.w], x[s4.w]);
    }
}

// ---- K5: block per f2-slot: bucket gather + row GEMM -> rowT (LDS), then
//          producer-side scatter: gacc[slot1] += rowT for matching eDr edges.
//          Hierarchical done; last block runs trivial parallel tail. ----
struct P7 {
    const int* bucket; const int* slotCnt; const float* agg0;
    const float* W0; const float* b0; const float* W1; const float* b1;
    const float* W2; const float* b2; const float* W3; const float* b3;
    const int* cnt2; const int* pos1;
    const int2* eDr; const int* cntD; const int* e1src; const int* cntE1;
    const int* cnt1; float* gacc; int* sub; int* top; float* out;
};

__global__ __launch_bounds__(256) void fused7_k(P7 p) {
    __shared__ float xv[128];
    __shared__ float part[256];
    __shared__ float rowA[64];
    __shared__ float rowH[128];
    __shared__ float rowT[64];
    __shared__ float t3s[MAXN1];
    __shared__ int lflag;
    const int tid = threadIdx.x;
    const int g = tid >> 6, j = tid & 63;
    int c2 = *p.cnt2; if (c2 > S2MAX) c2 = S2MAX;
    int cD = *p.cntD; if (cD > DMAX) cD = DMAX;
    const float w0 = p.W0[j], bb0 = p.b0[j];

    for (int b = blockIdx.x; b < c2; b += FGRID) {
        int cnt = p.slotCnt[b]; if (cnt > BK) cnt = BK;
        if (tid < cnt) xv[tid] = p.agg0[p.bucket[b * BK + tid]];   // parallel gather
        __syncthreads();
        float racc = 0.f;
        for (int m = g; m < cnt; m += 4) racc += lrelu(xv[m] * w0 + bb0);
        part[tid] = racc;
        __syncthreads();
        if (tid < 64)
            rowA[tid] = part[tid] + part[64 + tid] + part[128 + tid] + part[192 + tid];
        __syncthreads();
        if (tid < 128) {
            float h = p.b1[tid];
#pragma unroll
            for (int k = 0; k < 64; ++k) h += rowA[k] * p.W1[k * 128 + tid];
            rowH[tid] = lrelu(h);
        }
        __syncthreads();
        if (tid < 64) {
            float a2 = 0.f;
#pragma unroll
            for (int k = 0; k < 128; ++k) a2 += rowH[k] * p.W2[k * 64 + tid];
            rowT[tid] = a2;
        }
        __syncthreads();
        // producer-side scatter: edges with slot2 == b feed gacc[slot1]
        for (int base = 0; base < cD; base += 256) {
            int i = base + tid;
            int2 e = make_int2(-1, -1);
            if (i < cD) e = p.eDr[i];
            bool m = (e.x == b);
            unsigned long long bal = __ballot(m);
            while (bal) {
                int bit = __builtin_ctzll(bal); bal &= bal - 1;
                int sl1 = __shfl(e.y, bit, 64);
                if ((unsigned)sl1 < MAXN1)
                    atomicAdd(&p.gacc[sl1 * 64 + j], rowT[j]);
            }
        }
        __syncthreads();      // protect LDS before next slot
    }

    // -- hierarchical done: __syncthreads above + this one drain the block's
    //    atomics; sub-counter (32 arrivals, separate lines) -> top (8 arrivals).
    __syncthreads();
    if (tid == 0) {
        lflag = 0;
        int s = blockIdx.x & (SUBN - 1);
        int old = __hip_atomic_fetch_add(&p.sub[s * SUBW], 1,
                                         __ATOMIC_RELAXED, __HIP_MEMORY_SCOPE_AGENT);
        if (old == (FGRID / SUBN) - 1) {
            int o2 = __hip_atomic_fetch_add(p.top, 1,
                                            __ATOMIC_RELAXED, __HIP_MEMORY_SCOPE_AGENT);
            lflag = (o2 == SUBN - 1);
        }
    }
    __syncthreads();
    if (!lflag) return;

    // ---- trivial tail: parallel gacc read + layer-4 + output ----
    {
        int c1 = *p.cnt1;  if (c1 > MAXN1) c1 = MAXN1;
        int cE = *p.cntE1; if (cE > E1MAX) cE = E1MAX;
        int widx = tid >> 6;                   // 4 waves
        for (int slot = widx; slot < c1; slot += 4) {
            float v = lrelu(p.gacc[slot * 64 + j] + p.b2[j]) * p.W3[j];
            for (int off = 32; off > 0; off >>= 1) v += __shfl_down(v, off, 64);
            if (j == 0) t3s[slot] = v;
        }
        __syncthreads();
        if (tid < 64) {
            float ssum = 0.f;
            for (int k = tid; k < cE; k += 64) ssum += t3s[p.pos1[p.e1src[k]]];
            for (int off = 32; off > 0; off >>= 1) ssum += __shfl_down(ssum, off, 64);
            if (tid == 0) p.out[0] = lrelu(ssum + p.b3[0]);
        }
    }
}

extern "C" void kernel_launch(void* const* d_in, const int* in_sizes, int n_in,
                              void* d_out, int out_size, void* d_ws, size_t ws_size,
                              hipStream_t stream) {
    const float* x   = (const float*)d_in[0];
    const int*   src = (const int*)d_in[1];
    const int*   dst = (const int*)d_in[2];
    const float* W0 = (const float*)d_in[3];  const float* b0 = (const float*)d_in[4];
    const float* W1 = (const float*)d_in[5];  const float* b1 = (const float*)d_in[6];
    const float* W2 = (const float*)d_in[7];  const float* b2 = (const float*)d_in[8];
    const float* W3 = (const float*)d_in[9];  const float* b3 = (const float*)d_in[10];
    float* out = (float*)d_out;
    const int4* dst4 = (const int4*)dst;
    const int4* src4 = (const int4*)src;

    char* base = (char*)d_ws;
    size_t off = 0;
    auto take = [&](size_t bytes) { char* q = base + off; off += (bytes + 255) & ~(size_t)255; return q; };
    // ---- zeroed prefix (~77 KB memset) ----
    unsigned int* f1m = (unsigned int*)take(NMASKW * 4);
    unsigned int* f2m = (unsigned int*)take(NMASKW * 4);
    unsigned int* f3m = (unsigned int*)take(NMASKW * 4);
    int* cntE1 = (int*)take(4);
    int* cntD  = (int*)take(4);
    int* cnt1  = (int*)take(4);
    int* cnt2  = (int*)take(4);
    int* slotCnt = (int*)take((size_t)S2MAX * 4);
    int* sub   = (int*)take((size_t)SUBN * SUBW * 4);   // 8 counters, 256B apart
    int* top   = (int*)take(4);
    float* gacc = (float*)take((size_t)MAXN1 * 64 * 4); // 48 KB layer-3 accumulator
    size_t zero_bytes = off;
    // ---- uninitialized (written before read) ----
    float* agg0   = (float*)take((size_t)N_NODES * 4);
    int*   e1src  = (int*)take((size_t)E1MAX * 4);
    int2*  eD     = (int2*)take((size_t)DMAX * 8);
    int2*  eDr    = (int2*)take((size_t)DMAX * 8);
    int*   bucket = (int*)take((size_t)S2MAX * BK * 4);
    int*   pos1   = (int*)take((size_t)N_NODES * 4);
    int*   pos2   = (int*)take((size_t)N_NODES * 4);

    hipMemsetAsync(base, 0, zero_bytes, stream);

    scan1_k<<<SB, 256, 0, stream>>>(dst4, src, f1m, e1src, cntE1, pos1, cnt1);
    scan2_k<<<SB, 256, 0, stream>>>(dst4, src, f1m, f2m, pos1, pos2, cnt2, eD, cntD);
    scan3_k<<<SB, 256, 0, stream>>>(dst4, src, f2m, f3m, pos2, agg0, bucket, slotCnt);
    scan4_k<<<SB, 256, 0, stream>>>(dst4, src4, x, f3m, agg0, eD, cntD, pos2, eDr);

    P7 hp;
    hp.bucket = bucket; hp.slotCnt = slotCnt; hp.agg0 = agg0;
    hp.W0 = W0; hp.b0 = b0; hp.W1 = W1; hp.b1 = b1;
    hp.W2 = W2; hp.b2 = b2; hp.W3 = W3; hp.b3 = b3;
    hp.cnt2 = cnt2; hp.pos1 = pos1;
    hp.eDr = eDr; hp.cntD = cntD; hp.e1src = e1src; hp.cntE1 = cntE1;
    hp.cnt1 = cnt1; hp.gacc = gacc; hp.sub = sub; hp.top = top; hp.out = out;
    fused7_k<<<FGRID, 256, 0, stream>>>(hp);
}